// Round 9
// baseline (1393.451 us; speedup 1.0000x reference)
//
#include <hip/hip_runtime.h>
#include <hip/hip_bf16.h>
#include <math.h>

// LiquidNCA via bf16 MFMA, v3.1 = R8 structure + VALU-issue cuts:
//  - fast bf16 convert (finite-only round-half-up: bits+0x8000 >> 16) and
//    packed 2-at-a-time conversion for the delta stash. R8 was VALU-bound
//    (VALUBusy 54%, MfmaUtil 11.5%); __float2bfloat16's RNE+NaN path is ~6
//    VALU ops and ran ~66x/lane.
//  - sigmoid via v_rcp_f32 (~1 ulp) instead of the ~10-op exact-div sequence;
//    gated update as dv + beta*(sold-dv).
//  - hgrp pitch 32 -> 36 ushorts: row stride 72 B = 18 banks -> the per-r u16
//    writes spread over all 32 banks (was: 16-bank stride -> 8-way conflicts).
// Structure (verified R5/R8): comb layout [delta(0..15)|state(16..31)|x(32)|
// 0(33..47)] pitch 56; stage B A-window ch16 (K=[state,x,0..]); stage C
// A-window ch0 (K=[delta||state], full 32). tau x-contribution precomputed
// into tx (64 MiB ws). Step 0 skips state reads; step 9 fuses readout.

#define B_   32
#define H_   256
#define W_   256
#define PIT  56                // comb pitch in ushorts (112 B, 16B-aligned)
#define HP   36                // hgrp pitch in ushorts (72 B)

typedef unsigned short ushort_t;
typedef __attribute__((ext_vector_type(8))) short short8;
typedef __attribute__((ext_vector_type(4))) float float4v;

__device__ __forceinline__ unsigned fbits(float f) {
    union { float f; unsigned u; } v; v.f = f; return v.u;
}
__device__ __forceinline__ ushort_t f2bu(float f) {        // finite-only, RHU
    return (ushort_t)((fbits(f) + 0x8000u) >> 16);
}
__device__ __forceinline__ unsigned pack2(float lo, float hi) {
    return ((fbits(hi) + 0x8000u) & 0xFFFF0000u) | ((fbits(lo) + 0x8000u) >> 16);
}
__device__ __forceinline__ float bu2f(ushort_t u) {
    union { unsigned i; float f; } v; v.i = ((unsigned)u) << 16; return v.f;
}

// ---------------------------------------------------------------------------
// prep: Weff = W_up1 * W_perceive (fp32), beff; pack per-lane B-fragments.
// Frag layout (mfma_f32_16x16x32_bf16): B[k][n]: n=lane&15, k=(lane>>4)*8+j.
__global__ void prep(
    const float* __restrict__ wp,   // [32][17][9]
    const float* __restrict__ wu1,  // [16][32]
    const float* __restrict__ bu1,  // [16]
    const float* __restrict__ bp,   // [32]
    const float* __restrict__ wu2,  // [16][16]
    const float* __restrict__ wt,   // [16][33][9]
    ushort_t* __restrict__ wh1,     // [9][64][8]  stage-B weights
    ushort_t* __restrict__ wu2f,    // [64][8]     up2 weights
    ushort_t* __restrict__ wtn,     // [9][64][8]  stage-C tau weights (K=32)
    float* __restrict__ beffG)      // [16]
{
    __shared__ float Weff[16 * 153];   // [n][c(0..16)][t]
    const int tid = threadIdx.x;

    for (int i = tid; i < 16 * 153; i += 256) {
        int j = i / 153, rem = i % 153, c = rem / 9, t = rem % 9;
        float s = 0.f;
        for (int o = 0; o < 32; ++o)
            s += wu1[j * 32 + o] * wp[o * 153 + c * 9 + t];
        Weff[i] = s;
    }
    if (tid < 16) {
        float s = bu1[tid];
        for (int o = 0; o < 32; ++o) s += wu1[tid * 32 + o] * bp[o];
        beffG[tid] = s;
    }
    __syncthreads();

    // wh1: k<16 -> state (ref c=k+1); k==16 -> x (c=0); k>16 -> 0
    for (int i = tid; i < 9 * 64 * 8; i += 256) {
        int t = i / 512, lane = (i / 8) % 64, j = i % 8;
        int n = lane & 15, k = (lane >> 4) * 8 + j;
        float v = 0.f;
        if (k < 16) v = Weff[n * 153 + (k + 1) * 9 + t];
        else if (k == 16) v = Weff[n * 153 + t];
        wh1[i] = f2bu(v);
    }
    // wu2f: B[k][n] = wu2[n][k], k<16 else 0
    for (int i = tid; i < 512; i += 256) {
        int lane = i / 8, j = i % 8;
        int n = lane & 15, k = (lane >> 4) * 8 + j;
        wu2f[i] = (k < 16) ? f2bu(wu2[n * 16 + k]) : (ushort_t)0;
    }
    // wtn: stage-C A = [delta(16) || state(16)]:
    //   k<16 -> delta_k (ref c=17+k); k>=16 -> state_{k-16} (ref c=k-15)
    for (int i = tid; i < 9 * 64 * 8; i += 256) {
        int t = i / 512, lane = (i / 8) % 64, j = i % 8;
        int n = lane & 15, k = (lane >> 4) * 8 + j;
        int c = (k < 16) ? (17 + k) : (k - 15);
        wtn[i] = f2bu(wt[n * 297 + c * 9 + t]);
    }
}

// ---------------------------------------------------------------------------
// tx[pixel][16] = conv3x3(x, w_tau[:,c=0,:]) + b_tau_conv + b_tau  (bf16)
__global__ __launch_bounds__(256) void precompute_tx(
    const float* __restrict__ x,     // [B][H][W] fp32
    const float* __restrict__ wt,    // [16][33][9]
    const float* __restrict__ btc,   // [16]
    const float* __restrict__ bt,    // [16]
    ushort_t* __restrict__ tx)       // [B*H*W][16] bf16
{
    int p = blockIdx.x * 256 + threadIdx.x;
    int py = (p >> 8) & 255, px = p & 255;
    const float* xb = x + (p & ~0xFFFF);

    float xp[9];
#pragma unroll
    for (int t = 0; t < 9; ++t) {
        int gy = py + t / 3 - 1, gx = px + t % 3 - 1;
        bool in = ((unsigned)gy < 256u) & ((unsigned)gx < 256u);
        xp[t] = in ? xb[gy * 256 + gx] : 0.f;
    }
    short8 o0, o1;
#pragma unroll
    for (int j = 0; j < 16; ++j) {
        float tv = btc[j] + bt[j];
#pragma unroll
        for (int t = 0; t < 9; ++t) tv = fmaf(xp[t], wt[j * 297 + t], tv);
        if (j < 8) o0[j] = (short)f2bu(tv); else o1[j - 8] = (short)f2bu(tv);
    }
    ushort_t* dst = tx + (size_t)p * 16;
    *(short8*)(dst)     = o0;
    *(short8*)(dst + 8) = o1;
}

// ---------------------------------------------------------------------------
__global__ __launch_bounds__(256) void nca_step(
    const ushort_t* __restrict__ stIn,   // [B][H][W][16] bf16 (unused if first)
    ushort_t* __restrict__ stOut,        // [B][H][W][16] bf16 (unused if last)
    const float* __restrict__ xg,        // [B][H][W] fp32
    const ushort_t* __restrict__ txg,    // [B*H*W][16] bf16
    const ushort_t* __restrict__ wh1,
    const ushort_t* __restrict__ wu2f,
    const ushort_t* __restrict__ wtn,
    const float* __restrict__ beffG,
    const float* __restrict__ bu2G,
    const float* __restrict__ wrd,       // w_read [16]
    const float* __restrict__ brd,       // b_read [1]
    float* __restrict__ outg,            // [B][H][W] fp32 (used if last)
    int first, int last)
{
    __shared__ ushort_t comb[400 * PIT]; // 20x20 halo-2
    __shared__ ushort_t hgrp[64 * HP];   // h1 roundtrip, pitch 36 (72 B)
    __shared__ ushort_t dump[64];

    const int tid  = threadIdx.x;
    const int w    = tid >> 6, lane = tid & 63;
    const int m    = lane & 15, q = lane >> 4;
    const int gx0  = blockIdx.x * 16, gy0 = blockIdx.y * 16;
    const size_t pb = (size_t)blockIdx.z * 65536;
    const short8 z8 = {0, 0, 0, 0, 0, 0, 0, 0};
    const float4v z4 = {0.f, 0.f, 0.f, 0.f};

    // per-wave weight fragments (live in AGPRs; MFMA reads them directly)
    short8 wh1r[9], wtnr[9];
#pragma unroll
    for (int t = 0; t < 9; ++t) wh1r[t] = *(const short8*)(wh1 + (t * 64 + lane) * 8);
#pragma unroll
    for (int t = 0; t < 9; ++t) wtnr[t] = *(const short8*)(wtn + (t * 64 + lane) * 8);
    const short8 wu2r = *(const short8*)(wu2f + lane * 8);
    const float beff_l = beffG[m], bu2_l = bu2G[m];
    const float wr_l = wrd[m], br = brd[0];

    // ---- stage A: stage state(ch16..31), x(ch32), zeros(ch33..47) ----------
    for (int p = tid; p < 400; p += 256) {
        int ry = p / 20, rx = p - ry * 20;
        int gy = gy0 + ry - 2, gx = gx0 + rx - 2;
        ushort_t* row = comb + p * PIT;
        bool in = ((unsigned)gy < 256u) & ((unsigned)gx < 256u);
        if (in && !first) {
            const ushort_t* sp = stIn + (pb + gy * 256 + gx) * 16;
            *(short8*)(row + 16) = *(const short8*)(sp);
            *(short8*)(row + 24) = *(const short8*)(sp + 8);
        } else {
            *(short8*)(row + 16) = z8; *(short8*)(row + 24) = z8;
        }
        short8 xz = z8;
        if (in) xz[0] = (short)f2bu(xg[pb + gy * 256 + gx]);
        *(short8*)(row + 32) = xz;     // x + zeros ch33..39
        *(short8*)(row + 40) = z8;     // zeros ch40..47
    }
    if (tid < 128)  // zero hgrp ch16..31 of all 64 rows (up2 K-tail)
        *(short8*)(hgrp + (tid >> 1) * HP + 16 + (tid & 1) * 8) = z8;
    __syncthreads();

    // ---- stage B: h1 conv (A-window ch16: [state,x,0..]) -> up2 ------------
    uint2 stash[6];
    ushort_t* hg = hgrp + w * 16 * HP;
    for (int i = 0; i < 6; ++i) {
        int g = w + 4 * i; if (g >= 21) break;
        int idx = g * 16 + m; if (idx > 323) idx = 323;
        int py = idx / 18, px = idx - py * 18;
        const ushort_t* ab = comb + (py * 20 + px) * PIT + 16 + q * 8;
        float4v acc = z4;
#pragma unroll
        for (int t = 0; t < 9; ++t) {
            short8 a = *(const short8*)(ab + ((t / 3) * 20 + (t % 3)) * PIT);
            acc = __builtin_amdgcn_mfma_f32_16x16x32_bf16(a, wh1r[t], acc, 0, 0, 0);
        }
#pragma unroll
        for (int r = 0; r < 4; ++r) {
            float h = fmaxf(acc[r] + beff_l, 0.f);
            hg[(q * 4 + r) * HP + m] = f2bu(h);
        }
        __threadfence_block();
        short8 a2 = *(const short8*)(hg + m * HP + q * 8);
        float4v d = __builtin_amdgcn_mfma_f32_16x16x32_bf16(a2, wu2r, z4, 0, 0, 0);
        stash[i].x = pack2(d[0] + bu2_l, d[1] + bu2_l);
        stash[i].y = pack2(d[2] + bu2_l, d[3] + bu2_l);
        __threadfence_block();
    }
    __syncthreads();   // all stage-B comb reads done before delta lands

    // ---- deferred delta writes into comb ch0..15 ---------------------------
    for (int i = 0; i < 6; ++i) {
        int g = w + 4 * i; if (g >= 21) break;
#pragma unroll
        for (int r = 0; r < 4; ++r) {
            int idx = g * 16 + q * 4 + r;
            bool vld = idx < 324;
            int idc = vld ? idx : 323;
            int py = idc / 18, px = idc - py * 18;
            int gy = gy0 - 1 + py, gx = gx0 - 1 + px;
            bool im = vld & ((unsigned)gy < 256u) & ((unsigned)gx < 256u);
            unsigned uu = (r < 2) ? stash[i].x : stash[i].y;
            ushort_t v = (ushort_t)((r & 1) ? (uu >> 16) : (uu & 0xffffu));
            ushort_t* dst = vld ? (comb + ((py + 1) * 20 + (px + 1)) * PIT + m)
                                : (dump + lane);
            *dst = im ? v : (ushort_t)0;   // ref zero-pads delta outside image
        }
    }
    __syncthreads();

    // ---- stage C: tau conv (A-window ch0: [delta||state], K=32) ------------
    for (int i = 0; i < 4; ++i) {
        int g = w * 4 + i;                       // core row
        const ushort_t* cb = comb + ((g + 1) * 20 + (m + 1)) * PIT;
        float4v acc = z4;
#pragma unroll
        for (int t = 0; t < 9; ++t) {
            short8 a = *(const short8*)(cb + ((t / 3) * 20 + (t % 3)) * PIT + q * 8);
            acc = __builtin_amdgcn_mfma_f32_16x16x32_bf16(a, wtnr[t], acc, 0, 0, 0);
        }
        int gy = gy0 + g;
#pragma unroll
        for (int r = 0; r < 4; ++r) {
            int pxc = q * 4 + r;
            const ushort_t* cpx = comb + ((g + 2) * 20 + (pxc + 2)) * PIT;
            float sold = bu2f(cpx[16 + m]);
            float dv   = bu2f(cpx[m]);
            float txv  = bu2f(txg[(pb + gy * 256 + gx0 + pxc) * 16 + m]); // incl biases
            float tl   = acc[r] + txv;
            float e    = __expf(-tl);
            float bta  = __builtin_amdgcn_rcpf(1.f + e);      // ~1 ulp, fine
            bta = fminf(fmaxf(bta, 0.01f), 0.99f);
            float sn = dv + bta * (sold - dv);
            if (!last) {
                stOut[(pb + gy * 256 + gx0 + pxc) * 16 + m] = f2bu(sn);
            } else {
                // fused readout: sum over m (16-lane butterfly), then sigmoid
                float v = wr_l * sn;
                v += __shfl_xor(v, 1);
                v += __shfl_xor(v, 2);
                v += __shfl_xor(v, 4);
                v += __shfl_xor(v, 8);
                if (m == 0) {
                    float eo = __expf(-(v + br));
                    outg[pb + gy * 256 + gx0 + pxc] =
                        __builtin_amdgcn_rcpf(1.f + eo);
                }
            }
        }
    }
}

// ---------------------------------------------------------------------------
extern "C" void kernel_launch(void* const* d_in, const int* in_sizes, int n_in,
                              void* d_out, int out_size, void* d_ws, size_t ws_size,
                              hipStream_t stream)
{
    const float* x          = (const float*)d_in[0];
    const float* w_perceive = (const float*)d_in[1];
    const float* b_perceive = (const float*)d_in[2];
    const float* w_up1      = (const float*)d_in[3];
    const float* b_up1      = (const float*)d_in[4];
    const float* w_up2      = (const float*)d_in[5];
    const float* b_up2      = (const float*)d_in[6];
    const float* w_tau      = (const float*)d_in[7];
    const float* b_tau_conv = (const float*)d_in[8];
    const float* b_tau      = (const float*)d_in[9];
    const float* w_read     = (const float*)d_in[10];
    const float* b_read     = (const float*)d_in[11];
    // d_in[12] = n_steps = 10 (host-known; hard-coded for graph capture)
    float* out = (float*)d_out;

    const size_t stateElems = (size_t)B_ * H_ * W_ * 16;   // 33,554,432 bf16

    ushort_t* stA  = (ushort_t*)d_ws;
    ushort_t* stB  = stA + stateElems;
    ushort_t* txg  = stB + stateElems;         // 64 MiB
    ushort_t* wh1  = txg + stateElems;         // 4608
    ushort_t* wu2f = wh1 + 4608;               // 512
    ushort_t* wtn  = wu2f + 512;               // 4608
    float*    beffG = (float*)(wtn + 4608);    // 16

    const size_t needBytes = 3 * stateElems * sizeof(ushort_t)
                           + (4608 + 512 + 4608) * sizeof(ushort_t)
                           + 16 * sizeof(float);
    if (ws_size < needBytes) return;

    prep<<<dim3(1), dim3(256), 0, stream>>>(
        w_perceive, w_up1, b_up1, b_perceive, w_up2, w_tau,
        wh1, wu2f, wtn, beffG);
    precompute_tx<<<dim3(8192), dim3(256), 0, stream>>>(
        x, w_tau, b_tau_conv, b_tau, txg);

    ushort_t* cur = stA;
    ushort_t* nxt = stB;
    for (int s = 0; s < 10; ++s) {
        nca_step<<<dim3(16, 16, 32), dim3(256), 0, stream>>>(
            cur, nxt, x, txg, wh1, wu2f, wtn, beffG, b_up2,
            w_read, b_read, out, (s == 0) ? 1 : 0, (s == 9) ? 1 : 0);
        ushort_t* t = cur; cur = nxt; nxt = t;
    }
}

// Round 10
// 1182.182 us; speedup vs baseline: 1.1787x; 1.1787x over previous
//
#include <hip/hip_runtime.h>
#include <hip/hip_bf16.h>
#include <math.h>

// LiquidNCA via bf16 MFMA, v3.2 = R9 + occupancy lever (3 -> 4 blocks/CU).
// R9 post-mortem: VALU cuts dropped VALUBusy 54->44% but total unchanged ->
// not VALU-bound; latency/barrier-bound at 3 blocks/CU (48.5 KB LDS).
// Change: comb pitch 56 -> 40 ushorts. Stage B's A-window (ch16..47) has
// EXACTLY-ZERO weights for k=17..31, so those slots need only be finite:
// the window may spill into the next pixel's delta slots (ch0..7), which we
// zero-init in stage A (MFMA NaN-safety: 0 x NaN = NaN). comb 44.8 -> 32.0 KB,
// total LDS ~36.8 KB -> 4 blocks/CU.
// Structure (verified R5/R8/R9): [delta(0..15)|state(16..31)|x(32)|0(33..39)];
// stage B A-window ch16 (K=[state,x,...]); stage C A-window ch0
// (K=[delta||state], full 32). tau x-contribution precomputed into tx.
// Step 0 skips state reads; step 9 fuses readout via 16-lane butterfly.

#define B_   32
#define H_   256
#define W_   256
#define PIT  40                // comb pitch in ushorts (80 B, 16B-aligned)
#define HP   36                // hgrp pitch in ushorts (72 B)

typedef unsigned short ushort_t;
typedef __attribute__((ext_vector_type(8))) short short8;
typedef __attribute__((ext_vector_type(4))) float float4v;

__device__ __forceinline__ unsigned fbits(float f) {
    union { float f; unsigned u; } v; v.f = f; return v.u;
}
__device__ __forceinline__ ushort_t f2bu(float f) {        // finite-only, RHU
    return (ushort_t)((fbits(f) + 0x8000u) >> 16);
}
__device__ __forceinline__ unsigned pack2(float lo, float hi) {
    return ((fbits(hi) + 0x8000u) & 0xFFFF0000u) | ((fbits(lo) + 0x8000u) >> 16);
}
__device__ __forceinline__ float bu2f(ushort_t u) {
    union { unsigned i; float f; } v; v.i = ((unsigned)u) << 16; return v.f;
}

// ---------------------------------------------------------------------------
// prep: Weff = W_up1 * W_perceive (fp32), beff; pack per-lane B-fragments.
// Frag layout (mfma_f32_16x16x32_bf16): B[k][n]: n=lane&15, k=(lane>>4)*8+j.
__global__ void prep(
    const float* __restrict__ wp,   // [32][17][9]
    const float* __restrict__ wu1,  // [16][32]
    const float* __restrict__ bu1,  // [16]
    const float* __restrict__ bp,   // [32]
    const float* __restrict__ wu2,  // [16][16]
    const float* __restrict__ wt,   // [16][33][9]
    ushort_t* __restrict__ wh1,     // [9][64][8]  stage-B weights
    ushort_t* __restrict__ wu2f,    // [64][8]     up2 weights
    ushort_t* __restrict__ wtn,     // [9][64][8]  stage-C tau weights (K=32)
    float* __restrict__ beffG)      // [16]
{
    __shared__ float Weff[16 * 153];   // [n][c(0..16)][t]
    const int tid = threadIdx.x;

    for (int i = tid; i < 16 * 153; i += 256) {
        int j = i / 153, rem = i % 153, c = rem / 9, t = rem % 9;
        float s = 0.f;
        for (int o = 0; o < 32; ++o)
            s += wu1[j * 32 + o] * wp[o * 153 + c * 9 + t];
        Weff[i] = s;
    }
    if (tid < 16) {
        float s = bu1[tid];
        for (int o = 0; o < 32; ++o) s += wu1[tid * 32 + o] * bp[o];
        beffG[tid] = s;
    }
    __syncthreads();

    // wh1: k<16 -> state (ref c=k+1); k==16 -> x (c=0); k>16 -> 0 (MUST be 0:
    // those A-slots read pad/next-pixel-delta garbage values)
    for (int i = tid; i < 9 * 64 * 8; i += 256) {
        int t = i / 512, lane = (i / 8) % 64, j = i % 8;
        int n = lane & 15, k = (lane >> 4) * 8 + j;
        float v = 0.f;
        if (k < 16) v = Weff[n * 153 + (k + 1) * 9 + t];
        else if (k == 16) v = Weff[n * 153 + t];
        wh1[i] = f2bu(v);
    }
    // wu2f: B[k][n] = wu2[n][k], k<16 else 0
    for (int i = tid; i < 512; i += 256) {
        int lane = i / 8, j = i % 8;
        int n = lane & 15, k = (lane >> 4) * 8 + j;
        wu2f[i] = (k < 16) ? f2bu(wu2[n * 16 + k]) : (ushort_t)0;
    }
    // wtn: stage-C A = [delta(16) || state(16)]:
    //   k<16 -> delta_k (ref c=17+k); k>=16 -> state_{k-16} (ref c=k-15)
    for (int i = tid; i < 9 * 64 * 8; i += 256) {
        int t = i / 512, lane = (i / 8) % 64, j = i % 8;
        int n = lane & 15, k = (lane >> 4) * 8 + j;
        int c = (k < 16) ? (17 + k) : (k - 15);
        wtn[i] = f2bu(wt[n * 297 + c * 9 + t]);
    }
}

// ---------------------------------------------------------------------------
// tx[pixel][16] = conv3x3(x, w_tau[:,c=0,:]) + b_tau_conv + b_tau  (bf16)
__global__ __launch_bounds__(256) void precompute_tx(
    const float* __restrict__ x,     // [B][H][W] fp32
    const float* __restrict__ wt,    // [16][33][9]
    const float* __restrict__ btc,   // [16]
    const float* __restrict__ bt,    // [16]
    ushort_t* __restrict__ tx)       // [B*H*W][16] bf16
{
    int p = blockIdx.x * 256 + threadIdx.x;
    int py = (p >> 8) & 255, px = p & 255;
    const float* xb = x + (p & ~0xFFFF);

    float xp[9];
#pragma unroll
    for (int t = 0; t < 9; ++t) {
        int gy = py + t / 3 - 1, gx = px + t % 3 - 1;
        bool in = ((unsigned)gy < 256u) & ((unsigned)gx < 256u);
        xp[t] = in ? xb[gy * 256 + gx] : 0.f;
    }
    short8 o0, o1;
#pragma unroll
    for (int j = 0; j < 16; ++j) {
        float tv = btc[j] + bt[j];
#pragma unroll
        for (int t = 0; t < 9; ++t) tv = fmaf(xp[t], wt[j * 297 + t], tv);
        if (j < 8) o0[j] = (short)f2bu(tv); else o1[j - 8] = (short)f2bu(tv);
    }
    ushort_t* dst = tx + (size_t)p * 16;
    *(short8*)(dst)     = o0;
    *(short8*)(dst + 8) = o1;
}

// ---------------------------------------------------------------------------
__global__ __launch_bounds__(256) void nca_step(
    const ushort_t* __restrict__ stIn,   // [B][H][W][16] bf16 (unused if first)
    ushort_t* __restrict__ stOut,        // [B][H][W][16] bf16 (unused if last)
    const float* __restrict__ xg,        // [B][H][W] fp32
    const ushort_t* __restrict__ txg,    // [B*H*W][16] bf16
    const ushort_t* __restrict__ wh1,
    const ushort_t* __restrict__ wu2f,
    const ushort_t* __restrict__ wtn,
    const float* __restrict__ beffG,
    const float* __restrict__ bu2G,
    const float* __restrict__ wrd,       // w_read [16]
    const float* __restrict__ brd,       // b_read [1]
    float* __restrict__ outg,            // [B][H][W] fp32 (used if last)
    int first, int last)
{
    __shared__ ushort_t comb[400 * PIT + 8];  // 20x20 halo-2 (+tail pad for
                                              // pixel 399's spill window)
    __shared__ ushort_t hgrp[64 * HP];   // h1 roundtrip, pitch 36 (72 B)
    __shared__ ushort_t dump[64];

    const int tid  = threadIdx.x;
    const int w    = tid >> 6, lane = tid & 63;
    const int m    = lane & 15, q = lane >> 4;
    const int gx0  = blockIdx.x * 16, gy0 = blockIdx.y * 16;
    const size_t pb = (size_t)blockIdx.z * 65536;
    const short8 z8 = {0, 0, 0, 0, 0, 0, 0, 0};
    const float4v z4 = {0.f, 0.f, 0.f, 0.f};

    // per-wave weight fragments (live in AGPRs; MFMA reads them directly)
    short8 wh1r[9], wtnr[9];
#pragma unroll
    for (int t = 0; t < 9; ++t) wh1r[t] = *(const short8*)(wh1 + (t * 64 + lane) * 8);
#pragma unroll
    for (int t = 0; t < 9; ++t) wtnr[t] = *(const short8*)(wtn + (t * 64 + lane) * 8);
    const short8 wu2r = *(const short8*)(wu2f + lane * 8);
    const float beff_l = beffG[m], bu2_l = bu2G[m];
    const float wr_l = wrd[m], br = brd[0];

    // ---- stage A: zero delta ch0..7, stage state(16..31), x(32), 0(33..39) --
    for (int p = tid; p < 400; p += 256) {
        int ry = p / 20, rx = p - ry * 20;
        int gy = gy0 + ry - 2, gx = gx0 + rx - 2;
        ushort_t* row = comb + p * PIT;
        bool in = ((unsigned)gy < 256u) & ((unsigned)gx < 256u);
        *(short8*)(row) = z8;          // delta ch0..7 finite for stage-B spill
        if (in && !first) {
            const ushort_t* sp = stIn + (pb + gy * 256 + gx) * 16;
            *(short8*)(row + 16) = *(const short8*)(sp);
            *(short8*)(row + 24) = *(const short8*)(sp + 8);
        } else {
            *(short8*)(row + 16) = z8; *(short8*)(row + 24) = z8;
        }
        short8 xz = z8;
        if (in) xz[0] = (short)f2bu(xg[pb + gy * 256 + gx]);
        *(short8*)(row + 32) = xz;     // x + zeros ch33..39
    }
    if (tid == 0) *(short8*)(comb + 400 * PIT) = z8;   // tail pad
    if (tid < 128)  // zero hgrp ch16..31 of all 64 rows (up2 K-tail)
        *(short8*)(hgrp + (tid >> 1) * HP + 16 + (tid & 1) * 8) = z8;
    __syncthreads();

    // ---- stage B: h1 conv (A-window ch16: [state,x,...]) -> up2 ------------
    uint2 stash[6];
    ushort_t* hg = hgrp + w * 16 * HP;
    for (int i = 0; i < 6; ++i) {
        int g = w + 4 * i; if (g >= 21) break;
        int idx = g * 16 + m; if (idx > 323) idx = 323;
        int py = idx / 18, px = idx - py * 18;
        const ushort_t* ab = comb + (py * 20 + px) * PIT + 16 + q * 8;
        float4v acc = z4;
#pragma unroll
        for (int t = 0; t < 9; ++t) {
            short8 a = *(const short8*)(ab + ((t / 3) * 20 + (t % 3)) * PIT);
            acc = __builtin_amdgcn_mfma_f32_16x16x32_bf16(a, wh1r[t], acc, 0, 0, 0);
        }
#pragma unroll
        for (int r = 0; r < 4; ++r) {
            float h = fmaxf(acc[r] + beff_l, 0.f);
            hg[(q * 4 + r) * HP + m] = f2bu(h);
        }
        __threadfence_block();
        short8 a2 = *(const short8*)(hg + m * HP + q * 8);
        float4v d = __builtin_amdgcn_mfma_f32_16x16x32_bf16(a2, wu2r, z4, 0, 0, 0);
        stash[i].x = pack2(d[0] + bu2_l, d[1] + bu2_l);
        stash[i].y = pack2(d[2] + bu2_l, d[3] + bu2_l);
        __threadfence_block();
    }
    __syncthreads();   // all stage-B comb reads done before delta lands

    // ---- deferred delta writes into comb ch0..15 ---------------------------
    for (int i = 0; i < 6; ++i) {
        int g = w + 4 * i; if (g >= 21) break;
#pragma unroll
        for (int r = 0; r < 4; ++r) {
            int idx = g * 16 + q * 4 + r;
            bool vld = idx < 324;
            int idc = vld ? idx : 323;
            int py = idc / 18, px = idc - py * 18;
            int gy = gy0 - 1 + py, gx = gx0 - 1 + px;
            bool im = vld & ((unsigned)gy < 256u) & ((unsigned)gx < 256u);
            unsigned uu = (r < 2) ? stash[i].x : stash[i].y;
            ushort_t v = (ushort_t)((r & 1) ? (uu >> 16) : (uu & 0xffffu));
            ushort_t* dst = vld ? (comb + ((py + 1) * 20 + (px + 1)) * PIT + m)
                                : (dump + lane);
            *dst = im ? v : (ushort_t)0;   // ref zero-pads delta outside image
        }
    }
    __syncthreads();

    // ---- stage C: tau conv (A-window ch0: [delta||state], K=32) ------------
    for (int i = 0; i < 4; ++i) {
        int g = w * 4 + i;                       // core row
        const ushort_t* cb = comb + ((g + 1) * 20 + (m + 1)) * PIT;
        float4v acc = z4;
#pragma unroll
        for (int t = 0; t < 9; ++t) {
            short8 a = *(const short8*)(cb + ((t / 3) * 20 + (t % 3)) * PIT + q * 8);
            acc = __builtin_amdgcn_mfma_f32_16x16x32_bf16(a, wtnr[t], acc, 0, 0, 0);
        }
        int gy = gy0 + g;
#pragma unroll
        for (int r = 0; r < 4; ++r) {
            int pxc = q * 4 + r;
            const ushort_t* cpx = comb + ((g + 2) * 20 + (pxc + 2)) * PIT;
            float sold = bu2f(cpx[16 + m]);
            float dv   = bu2f(cpx[m]);
            float txv  = bu2f(txg[(pb + gy * 256 + gx0 + pxc) * 16 + m]); // incl biases
            float tl   = acc[r] + txv;
            float e    = __expf(-tl);
            float bta  = __builtin_amdgcn_rcpf(1.f + e);      // ~1 ulp, fine
            bta = fminf(fmaxf(bta, 0.01f), 0.99f);
            float sn = dv + bta * (sold - dv);
            if (!last) {
                stOut[(pb + gy * 256 + gx0 + pxc) * 16 + m] = f2bu(sn);
            } else {
                // fused readout: sum over m (16-lane butterfly), then sigmoid
                float v = wr_l * sn;
                v += __shfl_xor(v, 1);
                v += __shfl_xor(v, 2);
                v += __shfl_xor(v, 4);
                v += __shfl_xor(v, 8);
                if (m == 0) {
                    float eo = __expf(-(v + br));
                    outg[pb + gy * 256 + gx0 + pxc] =
                        __builtin_amdgcn_rcpf(1.f + eo);
                }
            }
        }
    }
}

// ---------------------------------------------------------------------------
extern "C" void kernel_launch(void* const* d_in, const int* in_sizes, int n_in,
                              void* d_out, int out_size, void* d_ws, size_t ws_size,
                              hipStream_t stream)
{
    const float* x          = (const float*)d_in[0];
    const float* w_perceive = (const float*)d_in[1];
    const float* b_perceive = (const float*)d_in[2];
    const float* w_up1      = (const float*)d_in[3];
    const float* b_up1      = (const float*)d_in[4];
    const float* w_up2      = (const float*)d_in[5];
    const float* b_up2      = (const float*)d_in[6];
    const float* w_tau      = (const float*)d_in[7];
    const float* b_tau_conv = (const float*)d_in[8];
    const float* b_tau      = (const float*)d_in[9];
    const float* w_read     = (const float*)d_in[10];
    const float* b_read     = (const float*)d_in[11];
    // d_in[12] = n_steps = 10 (host-known; hard-coded for graph capture)
    float* out = (float*)d_out;

    const size_t stateElems = (size_t)B_ * H_ * W_ * 16;   // 33,554,432 bf16

    ushort_t* stA  = (ushort_t*)d_ws;
    ushort_t* stB  = stA + stateElems;
    ushort_t* txg  = stB + stateElems;         // 64 MiB
    ushort_t* wh1  = txg + stateElems;         // 4608
    ushort_t* wu2f = wh1 + 4608;               // 512
    ushort_t* wtn  = wu2f + 512;               // 4608
    float*    beffG = (float*)(wtn + 4608);    // 16

    const size_t needBytes = 3 * stateElems * sizeof(ushort_t)
                           + (4608 + 512 + 4608) * sizeof(ushort_t)
                           + 16 * sizeof(float);
    if (ws_size < needBytes) return;

    prep<<<dim3(1), dim3(256), 0, stream>>>(
        w_perceive, w_up1, b_up1, b_perceive, w_up2, w_tau,
        wh1, wu2f, wtn, beffG);
    precompute_tx<<<dim3(8192), dim3(256), 0, stream>>>(
        x, w_tau, b_tau_conv, b_tau, txg);

    ushort_t* cur = stA;
    ushort_t* nxt = stB;
    for (int s = 0; s < 10; ++s) {
        nca_step<<<dim3(16, 16, 32), dim3(256), 0, stream>>>(
            cur, nxt, x, txg, wh1, wu2f, wtn, beffG, b_up2,
            w_read, b_read, out, (s == 0) ? 1 : 0, (s == 9) ? 1 : 0);
        ushort_t* t = cur; cur = nxt; nxt = t;
    }
}